// Round 5
// baseline (6761.271 us; speedup 1.0000x reference)
//
#include <hip/hip_runtime.h>
#include <hip/hip_bf16.h>
#include <math.h>

// DiffusionFlow: fused 10-step flow + log-det on MI355X.
// Round 5: 32x32x16 MFMA, 512 threads / 8 fat waves (64 cols each), 32 samples/WG.
// Xbuf rows: primal h 0-31, tangent u0 32-63, tangent u1 64-95; row stride 1024B,
// 16B-granule XOR swizzle byte ^= (row&7)<<4 on ALL accesses (conflict-free phases).

typedef float  f32x4  __attribute__((ext_vector_type(4)));
typedef float  f32x16 __attribute__((ext_vector_type(16)));
typedef __bf16 bf16x8 __attribute__((ext_vector_type(8)));

static __device__ __forceinline__ unsigned pkbf2(float a, float b) {
    unsigned short lo = __builtin_bit_cast(unsigned short, __float2bfloat16(a));
    unsigned short hi = __builtin_bit_cast(unsigned short, __float2bfloat16(b));
    return (unsigned)lo | ((unsigned)hi << 16);
}

// ---- pack W (512x512 row-major fp32) -> bf16 A-frag order for 32x32x16 ----
// out[(((c*16+nb)*64)+l)*8+j] = W[nb*32+(l&31)][c*16+(l>>5)*8+j]
__global__ void pack_w_kernel(const float* __restrict__ W,
                              __hip_bfloat16* __restrict__ out) {
    int i  = blockIdx.x * 512 + threadIdx.x;   // 0..262143
    int c  = i >> 13;
    int nb = (i >> 9) & 15;
    int l  = (i >> 3) & 63;
    int j  = i & 7;
    int n  = nb * 32 + (l & 31);
    int k  = c * 16 + ((l >> 5) << 3) + j;
    out[i] = __float2bfloat16(W[n * 512 + k]);
}

// ---- pack W0 cols 0,1 -> contiguous [512][2] fp32 ----
__global__ void pack_w0_kernel(const float* __restrict__ W0,
                               float* __restrict__ w01) {
    int o = threadIdx.x;
    w01[o * 2 + 0] = W0[o * 34 + 0];
    w01[o * 2 + 1] = W0[o * 34 + 1];
}

// ---- c_step[k][o] = b0[o] + W0[o,2:34] . temb(t_k) ----
__global__ void cstep_kernel(const float* __restrict__ W0,
                             const float* __restrict__ b0,
                             float* __restrict__ cst) {
    int k = blockIdx.x;
    int o = threadIdx.x;
    float t = (float)k * 0.1f;
    float acc = b0[o];
    #pragma unroll
    for (int j = 0; j < 16; ++j) {
        float f   = expf(-9.210340371976184f * (float)j / 16.0f);
        float arg = t * f;
        acc += W0[o * 34 + 2 + j]  * sinf(arg);
        acc += W0[o * 34 + 18 + j] * cosf(arg);
    }
    cst[k * 512 + o] = acc;
}

__global__ __launch_bounds__(512)
__attribute__((amdgpu_waves_per_eu(2, 2)))
void flow_kernel(const float* __restrict__ x,
                 const float* __restrict__ w01,
                 const float* __restrict__ cst,
                 const __hip_bfloat16* __restrict__ Wpk1,
                 const __hip_bfloat16* __restrict__ Wpk2,
                 const float* __restrict__ b1,
                 const float* __restrict__ b2,
                 const float* __restrict__ W3,
                 const float* __restrict__ b3v,
                 float* __restrict__ out)
{
    __shared__ __align__(16) __hip_bfloat16 Xbuf[96 * 512];  // 96 KB
    __shared__ float zbuf[32][2];
    __shared__ float ldbuf[32];

    const int tid  = threadIdx.x;
    const int lane = tid & 63;
    const int wid  = tid >> 6;        // 0..7 -> cols [wid*64, wid*64+64)
    const int l31  = lane & 31;
    const int hi   = lane >> 5;       // 0/1
    const int r7   = lane & 7;
    const int n0w  = wid << 6;
    const int wgs  = blockIdx.x << 5; // 32 samples per WG

    if (tid < 32) {
        zbuf[tid][0] = x[(wgs + tid) * 2 + 0];
        zbuf[tid][1] = x[(wgs + tid) * 2 + 1];
        ldbuf[tid]   = 0.0f;
    }

    // B-frag addressing: row = st*32 + l31; byte = row*1024 + ((c*32+hi*16)^(r7*16))
    int rowb[3];
    #pragma unroll
    for (int st = 0; st < 3; ++st) rowb[st] = (st * 32 + l31) << 10;
    const int hi16  = hi << 4;
    const int swz16 = r7 << 4;
    // A-frag: uint4 index = c*1024 + abase (+64 for second n-block)
    const int abase = (wid << 7) + lane;
    const uint4* Wp1 = (const uint4*)Wpk1;
    const uint4* Wp2 = (const uint4*)Wpk2;

    // L0/L3 work split: s0 = tid>>4 (sample), t16 = tid&15, strided chunks of 8
    const int s0  = tid >> 4;
    const int t16 = tid & 15;
    const int swz0 = (s0 & 7) << 4;

    __syncthreads();

    #pragma unroll 1
    for (int step = 0; step < 10; ++step) {
        // ---------- layer 0: rank-2 + step-constant, 32 outs/thread ----------
        {
            float z0 = zbuf[s0][0];
            float z1 = zbuf[s0][1];
            const float* cs = cst + (step << 9);
            char* base0 = (char*)Xbuf + (s0 << 10);
            #pragma unroll
            for (int m = 0; m < 4; ++m) {
                int ob = (t16 << 3) + (m << 7);    // element base, 8 outs
                unsigned ph[4], p0[4], p1[4];
                #pragma unroll
                for (int jj = 0; jj < 4; ++jj) {
                    float hv[2], u0v[2], u1v[2];
                    #pragma unroll
                    for (int k = 0; k < 2; ++k) {
                        int o = ob + jj * 2 + k;
                        float w00  = w01[o * 2 + 0];
                        float w01v = w01[o * 2 + 1];
                        float a   = fmaf(z0, w00, fmaf(z1, w01v, cs[o]));
                        float sig = 1.0f / (1.0f + __expf(-a));
                        float h   = a * sig;
                        float sp  = fmaf(h, 1.0f - sig, sig);   // silu'(a)
                        hv[k]  = h;
                        u0v[k] = sp * w00;
                        u1v[k] = sp * w01v;
                    }
                    ph[jj] = pkbf2(hv[0], hv[1]);
                    p0[jj] = pkbf2(u0v[0], u0v[1]);
                    p1[jj] = pkbf2(u1v[0], u1v[1]);
                }
                int off = (ob << 1) ^ swz0;        // (t16*16 + m*256) ^ swz0
                uint4 vph = {ph[0], ph[1], ph[2], ph[3]};
                uint4 vp0 = {p0[0], p0[1], p0[2], p0[3]};
                uint4 vp1 = {p1[0], p1[1], p1[2], p1[3]};
                *(uint4*)(base0 + off)              = vph;
                *(uint4*)(base0 + (32 << 10) + off) = vp0;
                *(uint4*)(base0 + (64 << 10) + off) = vp1;
            }
        }
        __syncthreads();

        // ---------- layers 1,2: D = W @ X^T via 32x32x16 MFMA ----------
        #pragma unroll 1
        for (int layer = 0; layer < 2; ++layer) {
            const uint4* __restrict__ Wp   = layer ? Wp2 : Wp1;
            const float* __restrict__ bias = layer ? b2  : b1;

            f32x16 acc[2][3];   // [n-tile of 32][stream]
            #pragma unroll
            for (int nt = 0; nt < 2; ++nt)
                #pragma unroll
                for (int st = 0; st < 3; ++st)
                    acc[nt][st] = (f32x16)(0.0f);

            uint4 a0[2], a1[2];                       // A depth-2 prefetch
            a0[0] = Wp[abase];        a1[0] = Wp[abase + 64];
            a0[1] = Wp[abase + 1024]; a1[1] = Wp[abase + 64 + 1024];

            #define KSTEP(c)                                                     \
            {                                                                    \
                int kx = (((c) << 5) | hi16) ^ swz16;                            \
                bf16x8 bf0 = __builtin_bit_cast(bf16x8,                          \
                    *(const uint4*)((const char*)Xbuf + rowb[0] + kx));          \
                bf16x8 bf1 = __builtin_bit_cast(bf16x8,                          \
                    *(const uint4*)((const char*)Xbuf + rowb[1] + kx));          \
                bf16x8 bf2 = __builtin_bit_cast(bf16x8,                          \
                    *(const uint4*)((const char*)Xbuf + rowb[2] + kx));          \
                bf16x8 av0 = __builtin_bit_cast(bf16x8, a0[(c) & 1]);            \
                bf16x8 av1 = __builtin_bit_cast(bf16x8, a1[(c) & 1]);            \
                acc[0][0] = __builtin_amdgcn_mfma_f32_32x32x16_bf16(av0, bf0, acc[0][0], 0, 0, 0); \
                acc[1][0] = __builtin_amdgcn_mfma_f32_32x32x16_bf16(av1, bf0, acc[1][0], 0, 0, 0); \
                acc[0][1] = __builtin_amdgcn_mfma_f32_32x32x16_bf16(av0, bf1, acc[0][1], 0, 0, 0); \
                acc[1][1] = __builtin_amdgcn_mfma_f32_32x32x16_bf16(av1, bf1, acc[1][1], 0, 0, 0); \
                acc[0][2] = __builtin_amdgcn_mfma_f32_32x32x16_bf16(av0, bf2, acc[0][2], 0, 0, 0); \
                acc[1][2] = __builtin_amdgcn_mfma_f32_32x32x16_bf16(av1, bf2, acc[1][2], 0, 0, 0); \
            }

            #pragma unroll 2
            for (int c = 0; c < 30; ++c) {
                uint4 na0 = Wp[abase + (c + 2) * 1024];
                uint4 na1 = Wp[abase + 64 + (c + 2) * 1024];
                KSTEP(c);
                a0[c & 1] = na0; a1[c & 1] = na1;
            }
            KSTEP(30);
            KSTEP(31);
            #undef KSTEP

            // bias: D rows for this lane: n = n0w + nt*32 + q*8 + hi*4 + rr
            f32x4 bv[2][4];
            #pragma unroll
            for (int nt = 0; nt < 2; ++nt)
                #pragma unroll
                for (int q = 0; q < 4; ++q)
                    bv[nt][q] = *(const f32x4*)(bias + n0w + nt * 32 + q * 8 + hi * 4);

            __syncthreads();   // all waves done reading Xbuf before overwrite

            // epilogue: silu + JVP coupling; writes to Xbuf[sample=l31][n]
            {
                char* pb = (char*)Xbuf + (l31 << 10);
                #pragma unroll
                for (int nt = 0; nt < 2; ++nt) {
                    #pragma unroll
                    for (int q = 0; q < 4; ++q) {
                        unsigned hw[2], u0w[2], u1w[2];
                        #pragma unroll
                        for (int r2 = 0; r2 < 2; ++r2) {
                            float hv[2], u0v[2], u1v[2];
                            #pragma unroll
                            for (int k = 0; k < 2; ++k) {
                                int reg = q * 4 + r2 * 2 + k;
                                float a   = acc[nt][0][reg] + bv[nt][q][r2 * 2 + k];
                                float sig = 1.0f / (1.0f + __expf(-a));
                                float h   = a * sig;
                                float sp  = fmaf(h, 1.0f - sig, sig);
                                hv[k]  = h;
                                u0v[k] = sp * acc[nt][1][reg];
                                u1v[k] = sp * acc[nt][2][reg];
                            }
                            hw[r2]  = pkbf2(hv[0], hv[1]);
                            u0w[r2] = pkbf2(u0v[0], u0v[1]);
                            u1w[r2] = pkbf2(u1v[0], u1v[1]);
                        }
                        // n base = n0w + nt*32 + q*8 + hi*4 -> byte = n*2
                        int off = ((n0w + nt * 32 + q * 8 + hi * 4) << 1) ^ swz16;
                        uint2 vh = {hw[0], hw[1]};
                        uint2 v0 = {u0w[0], u0w[1]};
                        uint2 v1 = {u1w[0], u1w[1]};
                        *(uint2*)(pb + off)              = vh;
                        *(uint2*)(pb + (32 << 10) + off) = v0;
                        *(uint2*)(pb + (64 << 10) + off) = v1;
                    }
                }
            }
            __syncthreads();
        }

        // ---------- layer 3: six length-512 dots + state update ----------
        {
            float d0 = 0.f, d1 = 0.f, d2 = 0.f, d3 = 0.f, d4 = 0.f, d5 = 0.f;
            #pragma unroll
            for (int p = 0; p < 4; ++p) {
                int eb = (t16 << 3) + (p << 7);    // element base, 8 elems
                float wa[8], wb[8];
                #pragma unroll
                for (int k = 0; k < 8; ++k) {
                    wa[k] = W3[eb + k];
                    wb[k] = W3[512 + eb + k];
                }
                #pragma unroll
                for (int st = 0; st < 3; ++st) {
                    int row = s0 + st * 32;
                    int off = (row << 10) + (((eb << 1)) ^ swz0);
                    uint4 v = *(const uint4*)((const char*)Xbuf + off);
                    unsigned uu[4] = {v.x, v.y, v.z, v.w};
                    float e[8];
                    #pragma unroll
                    for (int w = 0; w < 4; ++w) {
                        e[2*w]   = __uint_as_float(uu[w] << 16);
                        e[2*w+1] = __uint_as_float(uu[w] & 0xffff0000u);
                    }
                    float sa = 0.f, sb = 0.f;
                    #pragma unroll
                    for (int j = 0; j < 8; ++j) {
                        sa = fmaf(wa[j], e[j], sa);
                        sb = fmaf(wb[j], e[j], sb);
                    }
                    if      (st == 0) { d0 += sa; d1 += sb; }
                    else if (st == 1) { d2 += sa; d3 += sb; }
                    else              { d4 += sa; d5 += sb; }
                }
            }
            #pragma unroll
            for (int m = 1; m < 16; m <<= 1) {
                d0 += __shfl_xor(d0, m);
                d1 += __shfl_xor(d1, m);
                d2 += __shfl_xor(d2, m);
                d3 += __shfl_xor(d3, m);
                d4 += __shfl_xor(d4, m);
                d5 += __shfl_xor(d5, m);
            }
            if (t16 == 0) {
                float v0 = d0 + b3v[0];
                float v1 = d1 + b3v[1];
                float det = (1.0f + 0.1f * d2) * (1.0f + 0.1f * d5)
                          - 0.01f * d4 * d3;
                ldbuf[s0] += logf(fmaxf(fabsf(det), 1e-8f));
                zbuf[s0][0] += 0.1f * v0;
                zbuf[s0][1] += 0.1f * v1;
            }
        }
        __syncthreads();
    }

    if (tid < 32) {
        float z0 = zbuf[tid][0], z1 = zbuf[tid][1];
        out[wgs + tid] = -0.5f * (z0 * z0 + z1 * z1) - 1.8378770664093453f + ldbuf[tid];
    }
}

extern "C" void kernel_launch(void* const* d_in, const int* in_sizes, int n_in,
                              void* d_out, int out_size, void* d_ws, size_t ws_size,
                              hipStream_t stream) {
    const float* x  = (const float*)d_in[0];
    const float* W0 = (const float*)d_in[1];   // (512, 34)
    const float* b0 = (const float*)d_in[2];
    const float* W1 = (const float*)d_in[3];   // (512, 512)
    const float* b1 = (const float*)d_in[4];
    const float* W2 = (const float*)d_in[5];
    const float* b2 = (const float*)d_in[6];
    const float* W3 = (const float*)d_in[7];   // (2, 512)
    const float* b3 = (const float*)d_in[8];
    float* out = (float*)d_out;

    char* ws = (char*)d_ws;
    __hip_bfloat16* wpk1 = (__hip_bfloat16*)ws;                  // 512 KB
    __hip_bfloat16* wpk2 = (__hip_bfloat16*)(ws + (512u << 10)); // 512 KB
    float*          cstp = (float*)(ws + (1024u << 10));         // 20 KB
    float*          w01p = (float*)(ws + (1044u << 10));         // 4 KB

    pack_w_kernel<<<512, 512, 0, stream>>>(W1, wpk1);
    pack_w_kernel<<<512, 512, 0, stream>>>(W2, wpk2);
    cstep_kernel<<<10, 512, 0, stream>>>(W0, b0, cstp);
    pack_w0_kernel<<<1, 512, 0, stream>>>(W0, w01p);
    flow_kernel<<<131072 / 32, 512, 0, stream>>>(x, w01p, cstp, wpk1, wpk2,
                                                 b1, b2, W3, b3, out);
}